// Round 4
// baseline (61.673 us; speedup 1.0000x reference)
//
#include <hip/hip_runtime.h>
#include <hip/hip_bf16.h>

// Problem constants (match reference)
constexpr int P = 8192;
constexpr int G = 4096;
constexpr int BLK = 256;
constexpr int GSPLIT = 64;          // G-dimension parallel chunks
constexpr int CHUNK = G / GSPLIT;   // 64 gaussians per chunk
constexpr int PPT = 2;              // points per thread
constexpr int PBLK = BLK * PPT;     // 512 points per block
constexpr float LOG2E = 1.4426950408889634f;

// ---------------------------------------------------------------------------
// Kernel 1: per-Gaussian precompute. Packs, per gaussian (5 x float4):
//   v0: mean.x, mean.y, mean.z, w00
//   v1: w11, w22, w01, w02
//   v2: w12, a0, a1, a2
//   v3: a3, a4, a5, a6
//   v4: a7, a8, 0, 0
// wij = Mahalanobis coefficients with (-0.5*log2(e)) and off-diag 2x folded:
//   gauss = exp2(w00*dxx + w11*dyy + w22*dzz + w01*dxdy + w02*dxdz + w12*dydz)
// a_k = (signed SH constant) * sh_k * sigmoid(opacity).
// ---------------------------------------------------------------------------
__global__ __launch_bounds__(256) void precomp_kernel(
    const float* __restrict__ mean, const float* __restrict__ fdc,
    const float* __restrict__ frest, const float* __restrict__ scal,
    const float* __restrict__ rot, const float* __restrict__ opac,
    float4* __restrict__ pre) {
  int g = blockIdx.x * blockDim.x + threadIdx.x;
  if (g >= G) return;

  float qr = rot[g * 4 + 0], qx = rot[g * 4 + 1];
  float qy = rot[g * 4 + 2], qz = rot[g * 4 + 3];
  float qn = 1.0f / sqrtf(qr * qr + qx * qx + qy * qy + qz * qz);
  qr *= qn; qx *= qn; qy *= qn; qz *= qn;

  float R00 = 1.f - 2.f * (qy * qy + qz * qz);
  float R01 = 2.f * (qx * qy - qr * qz);
  float R02 = 2.f * (qx * qz + qr * qy);
  float R10 = 2.f * (qx * qy + qr * qz);
  float R11 = 1.f - 2.f * (qx * qx + qz * qz);
  float R12 = 2.f * (qy * qz - qr * qx);
  float R20 = 2.f * (qx * qz - qr * qy);
  float R21 = 2.f * (qy * qz + qr * qx);
  float R22 = 1.f - 2.f * (qx * qx + qy * qy);

  float sc0 = expf(scal[g * 3 + 0]);
  float sc1 = expf(scal[g * 3 + 1]);
  float sc2 = expf(scal[g * 3 + 2]);
  float iv0 = 1.0f / (sc0 * sc0);
  float iv1 = 1.0f / (sc1 * sc1);
  float iv2 = 1.0f / (sc2 * sc2);

  float s00 = R00 * R00 * iv0 + R01 * R01 * iv1 + R02 * R02 * iv2;
  float s11 = R10 * R10 * iv0 + R11 * R11 * iv1 + R12 * R12 * iv2;
  float s22 = R20 * R20 * iv0 + R21 * R21 * iv1 + R22 * R22 * iv2;
  float s01 = R00 * R10 * iv0 + R01 * R11 * iv1 + R02 * R12 * iv2;
  float s02 = R00 * R20 * iv0 + R01 * R21 * iv1 + R02 * R22 * iv2;
  float s12 = R10 * R20 * iv0 + R11 * R21 * iv1 + R12 * R22 * iv2;

  const float kD = -0.5f * LOG2E;
  const float kO = -LOG2E;

  float alpha = 1.0f / (1.0f + expf(-opac[g]));

  const float C0 = 0.28209479177387814f;
  const float C1 = 0.4886025119029199f;
  float a0 = C0 * fdc[g] * alpha;
  float a1 = -C1 * frest[g * 8 + 0] * alpha;
  float a2 =  C1 * frest[g * 8 + 1] * alpha;
  float a3 = -C1 * frest[g * 8 + 2] * alpha;
  float a4 =  1.0925484305920792f  * frest[g * 8 + 3] * alpha;
  float a5 = -1.0925484305920792f  * frest[g * 8 + 4] * alpha;
  float a6 =  0.31539156525252005f * frest[g * 8 + 5] * alpha;
  float a7 = -1.0925484305920792f  * frest[g * 8 + 6] * alpha;
  float a8 =  0.5462742152960396f  * frest[g * 8 + 7] * alpha;

  float mx = mean[g * 3 + 0], my = mean[g * 3 + 1], mz = mean[g * 3 + 2];

  pre[g * 5 + 0] = make_float4(mx, my, mz, kD * s00);
  pre[g * 5 + 1] = make_float4(kD * s11, kD * s22, kO * s01, kO * s02);
  pre[g * 5 + 2] = make_float4(kO * s12, a0, a1, a2);
  pre[g * 5 + 3] = make_float4(a3, a4, a5, a6);
  pre[g * 5 + 4] = make_float4(a7, a8, 0.f, 0.f);
}

// ---------------------------------------------------------------------------
// Kernel 2: main pair loop. Grid = (P/PBLK, GSPLIT) = (16, 64) = 1024 blocks.
// NO LDS: the gaussian data address depends only on blockIdx.y and the loop
// counter (wave-uniform), so hipcc scalarizes these loads to s_load_dwordxN
// -> coefficients live in SGPRs and feed v_fma_f32 as the free SGPR operand.
// Each thread owns PPT=2 points (2 independent dependency chains).
// SH is evaluated un-normalized: reuse dxx..dydz from the mahalanobis term,
//   feat = a0 + inv*lin + inv^2*quad,  with 2zz-xx-yy = 3*dzz - d2
// and inv = rsqrt(max(d2,1e-16)) ~= 1/(sqrt(d2)+1e-8) for this data.
// ---------------------------------------------------------------------------
__global__ __launch_bounds__(BLK) void main_kernel(
    const float* __restrict__ pos, const float4* __restrict__ pre,
    float* __restrict__ partial) {
  const int t = threadIdx.x;
  const int p0 = blockIdx.x * PBLK + t;
  const int p1 = p0 + BLK;
  const int c = blockIdx.y;

  const float4* __restrict__ gp = pre + (size_t)c * CHUNK * 5;

  const float q0x = pos[p0 * 3 + 0] * 2.0f - 1.0f;
  const float q0y = pos[p0 * 3 + 1] * 2.0f - 1.0f;
  const float q0z = pos[p0 * 3 + 2] * 2.0f - 1.0f;
  const float q1x = pos[p1 * 3 + 0] * 2.0f - 1.0f;
  const float q1y = pos[p1 * 3 + 1] * 2.0f - 1.0f;
  const float q1z = pos[p1 * 3 + 2] * 2.0f - 1.0f;

  float acc0 = 0.0f, acc1 = 0.0f;
#pragma unroll 4
  for (int gi = 0; gi < CHUNK; ++gi) {
    const float4 v0 = gp[gi * 5 + 0];
    const float4 v1 = gp[gi * 5 + 1];
    const float4 v2 = gp[gi * 5 + 2];
    const float4 v3 = gp[gi * 5 + 3];
    const float4 v4 = gp[gi * 5 + 4];

    // ---- point 0 ----
    {
      const float dx = q0x - v0.x, dy = q0y - v0.y, dz = q0z - v0.z;
      const float dxx = dx * dx, dyy = dy * dy, dzz = dz * dz;
      const float dxdy = dx * dy, dxdz = dx * dz, dydz = dy * dz;
      const float d2 = dxx + dyy + dzz;

      float m = v0.w * dxx;
      m = fmaf(v1.x, dyy, m);
      m = fmaf(v1.y, dzz, m);
      m = fmaf(v1.z, dxdy, m);
      m = fmaf(v1.w, dxdz, m);
      m = fmaf(v2.x, dydz, m);
      const float gauss = exp2f(m);

      const float inv = __builtin_amdgcn_rsqf(fmaxf(d2, 1e-16f));
      const float inv2 = inv * inv;

      float lin = v3.x * dx;                 // a3*dx
      lin = fmaf(v2.z, dy, lin);             // a1*dy
      lin = fmaf(v2.w, dz, lin);             // a2*dz

      float quad = v3.y * dxdy;              // a4*dxdy
      quad = fmaf(v3.z, dydz, quad);         // a5*dydz
      quad = fmaf(v3.w, fmaf(3.f, dzz, -d2), quad);  // a6*(3dzz-d2)
      quad = fmaf(v4.x, dxdz, quad);         // a7*dxdz
      quad = fmaf(v4.y, dxx - dyy, quad);    // a8*(dxx-dyy)

      float feat = fmaf(inv, lin, v2.y);     // a0 + inv*lin
      feat = fmaf(inv2, quad, feat);

      acc0 = fmaf(gauss, feat, acc0);
    }
    // ---- point 1 ----
    {
      const float dx = q1x - v0.x, dy = q1y - v0.y, dz = q1z - v0.z;
      const float dxx = dx * dx, dyy = dy * dy, dzz = dz * dz;
      const float dxdy = dx * dy, dxdz = dx * dz, dydz = dy * dz;
      const float d2 = dxx + dyy + dzz;

      float m = v0.w * dxx;
      m = fmaf(v1.x, dyy, m);
      m = fmaf(v1.y, dzz, m);
      m = fmaf(v1.z, dxdy, m);
      m = fmaf(v1.w, dxdz, m);
      m = fmaf(v2.x, dydz, m);
      const float gauss = exp2f(m);

      const float inv = __builtin_amdgcn_rsqf(fmaxf(d2, 1e-16f));
      const float inv2 = inv * inv;

      float lin = v3.x * dx;
      lin = fmaf(v2.z, dy, lin);
      lin = fmaf(v2.w, dz, lin);

      float quad = v3.y * dxdy;
      quad = fmaf(v3.z, dydz, quad);
      quad = fmaf(v3.w, fmaf(3.f, dzz, -d2), quad);
      quad = fmaf(v4.x, dxdz, quad);
      quad = fmaf(v4.y, dxx - dyy, quad);

      float feat = fmaf(inv, lin, v2.y);
      feat = fmaf(inv2, quad, feat);

      acc1 = fmaf(gauss, feat, acc1);
    }
  }

  partial[(size_t)c * P + p0] = acc0;
  partial[(size_t)c * P + p1] = acc1;
}

// ---------------------------------------------------------------------------
// Kernel 3: deterministic reduction over GSPLIT partials.
// ---------------------------------------------------------------------------
__global__ __launch_bounds__(BLK) void reduce_kernel(
    const float* __restrict__ partial, float* __restrict__ out) {
  const int p = blockIdx.x * BLK + threadIdx.x;
  float s = 0.0f;
#pragma unroll
  for (int c = 0; c < GSPLIT; ++c) s += partial[(size_t)c * P + p];
  out[p] = s;
}

extern "C" void kernel_launch(void* const* d_in, const int* in_sizes, int n_in,
                              void* d_out, int out_size, void* d_ws, size_t ws_size,
                              hipStream_t stream) {
  const float* pos   = (const float*)d_in[0];  // position_rx (P,3)
  const float* mean  = (const float*)d_in[1];  // mean (G,3)
  const float* fdc   = (const float*)d_in[2];  // features_dc (G,1,1)
  const float* frest = (const float*)d_in[3];  // features_rest (G,1,8)
  const float* scal  = (const float*)d_in[4];  // scaling (G,3)
  const float* rot   = (const float*)d_in[5];  // rotation (G,4)
  const float* opac  = (const float*)d_in[6];  // opacity (G,1)
  float* out = (float*)d_out;                  // (P,1) fp32

  float4* pre = (float4*)d_ws;                            // G*5*16 = 320 KB
  float* partial = (float*)((char*)d_ws + (size_t)G * 5 * sizeof(float4));  // GSPLIT*P*4 = 2 MB

  precomp_kernel<<<G / BLK, BLK, 0, stream>>>(mean, fdc, frest, scal, rot, opac, pre);
  main_kernel<<<dim3(P / PBLK, GSPLIT), BLK, 0, stream>>>(pos, pre, partial);
  reduce_kernel<<<P / BLK, BLK, 0, stream>>>(partial, out);
}

// Round 5
// 52.520 us; speedup vs baseline: 1.1743x; 1.1743x over previous
//
#include <hip/hip_runtime.h>
#include <hip/hip_bf16.h>

// Problem constants (match reference)
constexpr int P = 8192;
constexpr int G = 4096;
constexpr int BLK = 256;
constexpr int GSPLIT = 128;         // G-dimension parallel chunks
constexpr int CHUNK = G / GSPLIT;   // 32 gaussians per chunk
constexpr int PPT = 4;              // points per thread (amortize coeff fetch)
constexpr int PBLK = BLK * PPT;     // 1024 points per block
constexpr float LOG2E = 1.4426950408889634f;

// ---------------------------------------------------------------------------
// Kernel 1: per-Gaussian precompute. Packs, per gaussian (5 x float4):
//   v0: mean.x, mean.y, mean.z, w00
//   v1: w11, w22, w01, w02
//   v2: w12, a0, a1, a2
//   v3: a3, a4, a5, a6
//   v4: a7, a8, 0, 0
// wij = Mahalanobis coefficients with (-0.5*log2(e)) and off-diag 2x folded:
//   gauss = exp2(w00*dxx + w11*dyy + w22*dzz + w01*dxdy + w02*dxdz + w12*dydz)
// a_k = (signed SH constant) * sh_k * sigmoid(opacity).
// ---------------------------------------------------------------------------
__global__ __launch_bounds__(256) void precomp_kernel(
    const float* __restrict__ mean, const float* __restrict__ fdc,
    const float* __restrict__ frest, const float* __restrict__ scal,
    const float* __restrict__ rot, const float* __restrict__ opac,
    float4* __restrict__ pre) {
  int g = blockIdx.x * blockDim.x + threadIdx.x;
  if (g >= G) return;

  float qr = rot[g * 4 + 0], qx = rot[g * 4 + 1];
  float qy = rot[g * 4 + 2], qz = rot[g * 4 + 3];
  float qn = 1.0f / sqrtf(qr * qr + qx * qx + qy * qy + qz * qz);
  qr *= qn; qx *= qn; qy *= qn; qz *= qn;

  float R00 = 1.f - 2.f * (qy * qy + qz * qz);
  float R01 = 2.f * (qx * qy - qr * qz);
  float R02 = 2.f * (qx * qz + qr * qy);
  float R10 = 2.f * (qx * qy + qr * qz);
  float R11 = 1.f - 2.f * (qx * qx + qz * qz);
  float R12 = 2.f * (qy * qz - qr * qx);
  float R20 = 2.f * (qx * qz - qr * qy);
  float R21 = 2.f * (qy * qz + qr * qx);
  float R22 = 1.f - 2.f * (qx * qx + qy * qy);

  float sc0 = expf(scal[g * 3 + 0]);
  float sc1 = expf(scal[g * 3 + 1]);
  float sc2 = expf(scal[g * 3 + 2]);
  float iv0 = 1.0f / (sc0 * sc0);
  float iv1 = 1.0f / (sc1 * sc1);
  float iv2 = 1.0f / (sc2 * sc2);

  float s00 = R00 * R00 * iv0 + R01 * R01 * iv1 + R02 * R02 * iv2;
  float s11 = R10 * R10 * iv0 + R11 * R11 * iv1 + R12 * R12 * iv2;
  float s22 = R20 * R20 * iv0 + R21 * R21 * iv1 + R22 * R22 * iv2;
  float s01 = R00 * R10 * iv0 + R01 * R11 * iv1 + R02 * R12 * iv2;
  float s02 = R00 * R20 * iv0 + R01 * R21 * iv1 + R02 * R22 * iv2;
  float s12 = R10 * R20 * iv0 + R11 * R21 * iv1 + R12 * R22 * iv2;

  const float kD = -0.5f * LOG2E;
  const float kO = -LOG2E;

  float alpha = 1.0f / (1.0f + expf(-opac[g]));

  const float C0 = 0.28209479177387814f;
  const float C1 = 0.4886025119029199f;
  float a0 = C0 * fdc[g] * alpha;
  float a1 = -C1 * frest[g * 8 + 0] * alpha;
  float a2 =  C1 * frest[g * 8 + 1] * alpha;
  float a3 = -C1 * frest[g * 8 + 2] * alpha;
  float a4 =  1.0925484305920792f  * frest[g * 8 + 3] * alpha;
  float a5 = -1.0925484305920792f  * frest[g * 8 + 4] * alpha;
  float a6 =  0.31539156525252005f * frest[g * 8 + 5] * alpha;
  float a7 = -1.0925484305920792f  * frest[g * 8 + 6] * alpha;
  float a8 =  0.5462742152960396f  * frest[g * 8 + 7] * alpha;

  float mx = mean[g * 3 + 0], my = mean[g * 3 + 1], mz = mean[g * 3 + 2];

  pre[g * 5 + 0] = make_float4(mx, my, mz, kD * s00);
  pre[g * 5 + 1] = make_float4(kD * s11, kD * s22, kO * s01, kO * s02);
  pre[g * 5 + 2] = make_float4(kO * s12, a0, a1, a2);
  pre[g * 5 + 3] = make_float4(a3, a4, a5, a6);
  pre[g * 5 + 4] = make_float4(a7, a8, 0.f, 0.f);
}

// ---------------------------------------------------------------------------
// Kernel 2: main pair loop. Grid = (P/PBLK, GSPLIT) = (8, 128) = 1024 blocks
// (4 blocks/CU, 16 waves/CU). NO LDS: gaussian-coefficient addresses depend
// only on blockIdx.y and the loop counter (wave-uniform) so they can live in
// SGPRs; each thread owns PPT=4 points -> the 80 B/gaussian fetch amortizes
// over ~128 VALU ops and gives 4 independent dependency chains.
// SH evaluated un-normalized (reuse mahalanobis cross terms):
//   feat = a0 + inv*lin + inv^2*quad,  2zz-xx-yy = 3*dzz - d2,
//   inv = rsqrt(max(d2,1e-16)) ~= 1/(sqrt(d2)+1e-8).
// ---------------------------------------------------------------------------
__global__ __launch_bounds__(BLK) void main_kernel(
    const float* __restrict__ pos, const float4* __restrict__ pre,
    float* __restrict__ partial) {
  const int t = threadIdx.x;
  const int pbase = blockIdx.x * PBLK + t;
  const int c = blockIdx.y;

  const float4* __restrict__ gp = pre + (size_t)c * CHUNK * 5;

  float px[PPT], py[PPT], pz[PPT], acc[PPT];
#pragma unroll
  for (int k = 0; k < PPT; ++k) {
    const int p = pbase + k * BLK;
    px[k] = pos[p * 3 + 0] * 2.0f - 1.0f;
    py[k] = pos[p * 3 + 1] * 2.0f - 1.0f;
    pz[k] = pos[p * 3 + 2] * 2.0f - 1.0f;
    acc[k] = 0.0f;
  }

#pragma unroll 2
  for (int gi = 0; gi < CHUNK; ++gi) {
    const float4 v0 = gp[gi * 5 + 0];
    const float4 v1 = gp[gi * 5 + 1];
    const float4 v2 = gp[gi * 5 + 2];
    const float4 v3 = gp[gi * 5 + 3];
    const float4 v4 = gp[gi * 5 + 4];

#pragma unroll
    for (int k = 0; k < PPT; ++k) {
      const float dx = px[k] - v0.x, dy = py[k] - v0.y, dz = pz[k] - v0.z;
      const float dxx = dx * dx, dyy = dy * dy, dzz = dz * dz;
      const float dxdy = dx * dy, dxdz = dx * dz, dydz = dy * dz;
      const float d2 = dxx + dyy + dzz;

      float m = v0.w * dxx;
      m = fmaf(v1.x, dyy, m);
      m = fmaf(v1.y, dzz, m);
      m = fmaf(v1.z, dxdy, m);
      m = fmaf(v1.w, dxdz, m);
      m = fmaf(v2.x, dydz, m);
      const float gauss = exp2f(m);

      const float inv = __builtin_amdgcn_rsqf(fmaxf(d2, 1e-16f));
      const float inv2 = inv * inv;

      float lin = v3.x * dx;                 // a3*dx
      lin = fmaf(v2.z, dy, lin);             // a1*dy
      lin = fmaf(v2.w, dz, lin);             // a2*dz

      float quad = v3.y * dxdy;              // a4*dxdy
      quad = fmaf(v3.z, dydz, quad);         // a5*dydz
      quad = fmaf(v3.w, fmaf(3.f, dzz, -d2), quad);  // a6*(3dzz-d2)
      quad = fmaf(v4.x, dxdz, quad);         // a7*dxdz
      quad = fmaf(v4.y, dxx - dyy, quad);    // a8*(dxx-dyy)

      float feat = fmaf(inv, lin, v2.y);     // a0 + inv*lin
      feat = fmaf(inv2, quad, feat);

      acc[k] = fmaf(gauss, feat, acc[k]);
    }
  }

#pragma unroll
  for (int k = 0; k < PPT; ++k) {
    partial[(size_t)c * P + pbase + k * BLK] = acc[k];
  }
}

// ---------------------------------------------------------------------------
// Kernel 3: deterministic reduction over GSPLIT partials.
// 64-thread blocks -> 128 blocks spread across CUs for latency hiding.
// ---------------------------------------------------------------------------
constexpr int BLK_R = 64;
__global__ __launch_bounds__(BLK_R) void reduce_kernel(
    const float* __restrict__ partial, float* __restrict__ out) {
  const int p = blockIdx.x * BLK_R + threadIdx.x;
  float s0 = 0.0f, s1 = 0.0f, s2 = 0.0f, s3 = 0.0f;
#pragma unroll 4
  for (int c = 0; c < GSPLIT; c += 4) {
    s0 += partial[(size_t)(c + 0) * P + p];
    s1 += partial[(size_t)(c + 1) * P + p];
    s2 += partial[(size_t)(c + 2) * P + p];
    s3 += partial[(size_t)(c + 3) * P + p];
  }
  out[p] = (s0 + s1) + (s2 + s3);
}

extern "C" void kernel_launch(void* const* d_in, const int* in_sizes, int n_in,
                              void* d_out, int out_size, void* d_ws, size_t ws_size,
                              hipStream_t stream) {
  const float* pos   = (const float*)d_in[0];  // position_rx (P,3)
  const float* mean  = (const float*)d_in[1];  // mean (G,3)
  const float* fdc   = (const float*)d_in[2];  // features_dc (G,1,1)
  const float* frest = (const float*)d_in[3];  // features_rest (G,1,8)
  const float* scal  = (const float*)d_in[4];  // scaling (G,3)
  const float* rot   = (const float*)d_in[5];  // rotation (G,4)
  const float* opac  = (const float*)d_in[6];  // opacity (G,1)
  float* out = (float*)d_out;                  // (P,1) fp32

  float4* pre = (float4*)d_ws;                            // G*5*16 = 320 KB
  float* partial = (float*)((char*)d_ws + (size_t)G * 5 * sizeof(float4));  // GSPLIT*P*4 = 4 MB

  precomp_kernel<<<G / BLK, BLK, 0, stream>>>(mean, fdc, frest, scal, rot, opac, pre);
  main_kernel<<<dim3(P / PBLK, GSPLIT), BLK, 0, stream>>>(pos, pre, partial);
  reduce_kernel<<<P / BLK_R, BLK_R, 0, stream>>>(partial, out);
}

// Round 6
// 45.983 us; speedup vs baseline: 1.3412x; 1.1422x over previous
//
#include <hip/hip_runtime.h>
#include <hip/hip_bf16.h>

// Problem constants (match reference)
constexpr int P = 8192;
constexpr int G = 4096;
constexpr int BLK = 256;
constexpr int GSPLIT = 128;         // G-dimension parallel chunks
constexpr int CHUNK = G / GSPLIT;   // 32 gaussians per chunk
constexpr int PPT = 4;              // points per thread
constexpr int PBLK = BLK * PPT;     // 1024 points per block
constexpr float LOG2E = 1.4426950408889634f;

// ---------------------------------------------------------------------------
// Fused kernel: per-block gaussian precompute (first CHUNK threads; 8x
// redundant across blockIdx.x but ~500 cycles) -> LDS -> VALU-bound pair
// loop. Coefficients per gaussian (5 x float4 in LDS):
//   v0: mean.x, mean.y, mean.z, w00
//   v1: w11, w22, w01, w02
//   v2: w12, a0, a1, a2
//   v3: a3, a4, a5, a6
//   v4: a7, a8, 0, 0
// wij = Mahalanobis coefficients with (-0.5*log2(e)) and off-diag 2x folded:
//   gauss = exp2(w00*dxx + w11*dyy + w22*dzz + w01*dxdy + w02*dxdz + w12*dydz)
// a_k = (signed SH constant) * sh_k * sigmoid(opacity).
// SH evaluated un-normalized (reuse mahalanobis cross terms):
//   feat = a0 + inv*lin + inv^2*quad,  2zz-xx-yy = 3*dzz - d2,
//   inv = rsqrt(max(d2,1e-16)) ~= 1/(sqrt(d2)+1e-8).
// LDS cost/gauss-iter: 5 x ds_read_b128 broadcast ~60 cyc/wave vs
// 4 pts x 31 VALU x 2 cyc = 248 cyc -> VALU-bound by ~4x.
// ---------------------------------------------------------------------------
__global__ __launch_bounds__(BLK) void fused_main(
    const float* __restrict__ pos,
    const float* __restrict__ mean, const float* __restrict__ fdc,
    const float* __restrict__ frest, const float* __restrict__ scal,
    const float* __restrict__ rot, const float* __restrict__ opac,
    float* __restrict__ partial) {
  __shared__ float4 sg[CHUNK * 5];

  const int t = threadIdx.x;
  const int c = blockIdx.y;
  const int pbase = blockIdx.x * PBLK + t;

  // Issue the point loads first so their latency overlaps the precompute.
  float px[PPT], py[PPT], pz[PPT], acc[PPT];
#pragma unroll
  for (int k = 0; k < PPT; ++k) {
    const int p = pbase + k * BLK;
    px[k] = pos[p * 3 + 0] * 2.0f - 1.0f;
    py[k] = pos[p * 3 + 1] * 2.0f - 1.0f;
    pz[k] = pos[p * 3 + 2] * 2.0f - 1.0f;
    acc[k] = 0.0f;
  }

  // In-block precompute of this chunk's 32 gaussians.
  if (t < CHUNK) {
    const int g = c * CHUNK + t;

    float qr = rot[g * 4 + 0], qx = rot[g * 4 + 1];
    float qy = rot[g * 4 + 2], qz = rot[g * 4 + 3];
    float qn = 1.0f / sqrtf(qr * qr + qx * qx + qy * qy + qz * qz);
    qr *= qn; qx *= qn; qy *= qn; qz *= qn;

    float R00 = 1.f - 2.f * (qy * qy + qz * qz);
    float R01 = 2.f * (qx * qy - qr * qz);
    float R02 = 2.f * (qx * qz + qr * qy);
    float R10 = 2.f * (qx * qy + qr * qz);
    float R11 = 1.f - 2.f * (qx * qx + qz * qz);
    float R12 = 2.f * (qy * qz - qr * qx);
    float R20 = 2.f * (qx * qz - qr * qy);
    float R21 = 2.f * (qy * qz + qr * qx);
    float R22 = 1.f - 2.f * (qx * qx + qy * qy);

    float sc0 = expf(scal[g * 3 + 0]);
    float sc1 = expf(scal[g * 3 + 1]);
    float sc2 = expf(scal[g * 3 + 2]);
    float iv0 = 1.0f / (sc0 * sc0);
    float iv1 = 1.0f / (sc1 * sc1);
    float iv2 = 1.0f / (sc2 * sc2);

    float s00 = R00 * R00 * iv0 + R01 * R01 * iv1 + R02 * R02 * iv2;
    float s11 = R10 * R10 * iv0 + R11 * R11 * iv1 + R12 * R12 * iv2;
    float s22 = R20 * R20 * iv0 + R21 * R21 * iv1 + R22 * R22 * iv2;
    float s01 = R00 * R10 * iv0 + R01 * R11 * iv1 + R02 * R12 * iv2;
    float s02 = R00 * R20 * iv0 + R01 * R21 * iv1 + R02 * R22 * iv2;
    float s12 = R10 * R20 * iv0 + R11 * R21 * iv1 + R12 * R22 * iv2;

    const float kD = -0.5f * LOG2E;
    const float kO = -LOG2E;

    float alpha = 1.0f / (1.0f + expf(-opac[g]));

    const float C0 = 0.28209479177387814f;
    const float C1 = 0.4886025119029199f;
    float a0 = C0 * fdc[g] * alpha;
    float a1 = -C1 * frest[g * 8 + 0] * alpha;
    float a2 =  C1 * frest[g * 8 + 1] * alpha;
    float a3 = -C1 * frest[g * 8 + 2] * alpha;
    float a4 =  1.0925484305920792f  * frest[g * 8 + 3] * alpha;
    float a5 = -1.0925484305920792f  * frest[g * 8 + 4] * alpha;
    float a6 =  0.31539156525252005f * frest[g * 8 + 5] * alpha;
    float a7 = -1.0925484305920792f  * frest[g * 8 + 6] * alpha;
    float a8 =  0.5462742152960396f  * frest[g * 8 + 7] * alpha;

    float mx = mean[g * 3 + 0], my = mean[g * 3 + 1], mz = mean[g * 3 + 2];

    sg[t * 5 + 0] = make_float4(mx, my, mz, kD * s00);
    sg[t * 5 + 1] = make_float4(kD * s11, kD * s22, kO * s01, kO * s02);
    sg[t * 5 + 2] = make_float4(kO * s12, a0, a1, a2);
    sg[t * 5 + 3] = make_float4(a3, a4, a5, a6);
    sg[t * 5 + 4] = make_float4(a7, a8, 0.f, 0.f);
  }

  __syncthreads();

#pragma unroll 2
  for (int gi = 0; gi < CHUNK; ++gi) {
    const float4 v0 = sg[gi * 5 + 0];
    const float4 v1 = sg[gi * 5 + 1];
    const float4 v2 = sg[gi * 5 + 2];
    const float4 v3 = sg[gi * 5 + 3];
    const float4 v4 = sg[gi * 5 + 4];

#pragma unroll
    for (int k = 0; k < PPT; ++k) {
      const float dx = px[k] - v0.x, dy = py[k] - v0.y, dz = pz[k] - v0.z;
      const float dxx = dx * dx, dyy = dy * dy, dzz = dz * dz;
      const float dxdy = dx * dy, dxdz = dx * dz, dydz = dy * dz;
      const float d2 = dxx + dyy + dzz;

      float m = v0.w * dxx;
      m = fmaf(v1.x, dyy, m);
      m = fmaf(v1.y, dzz, m);
      m = fmaf(v1.z, dxdy, m);
      m = fmaf(v1.w, dxdz, m);
      m = fmaf(v2.x, dydz, m);
      const float gauss = exp2f(m);

      const float inv = __builtin_amdgcn_rsqf(fmaxf(d2, 1e-16f));
      const float inv2 = inv * inv;

      float lin = v3.x * dx;                 // a3*dx
      lin = fmaf(v2.z, dy, lin);             // a1*dy
      lin = fmaf(v2.w, dz, lin);             // a2*dz

      float quad = v3.y * dxdy;              // a4*dxdy
      quad = fmaf(v3.z, dydz, quad);         // a5*dydz
      quad = fmaf(v3.w, fmaf(3.f, dzz, -d2), quad);  // a6*(3dzz-d2)
      quad = fmaf(v4.x, dxdz, quad);         // a7*dxdz
      quad = fmaf(v4.y, dxx - dyy, quad);    // a8*(dxx-dyy)

      float feat = fmaf(inv, lin, v2.y);     // a0 + inv*lin
      feat = fmaf(inv2, quad, feat);

      acc[k] = fmaf(gauss, feat, acc[k]);
    }
  }

#pragma unroll
  for (int k = 0; k < PPT; ++k) {
    partial[(size_t)c * P + pbase + k * BLK] = acc[k];
  }
}

// ---------------------------------------------------------------------------
// Deterministic reduction over GSPLIT partials. 32 blocks x 256 threads,
// lane-coalesced rows, 4 independent accumulator chains.
// ---------------------------------------------------------------------------
__global__ __launch_bounds__(BLK) void reduce_kernel(
    const float* __restrict__ partial, float* __restrict__ out) {
  const int p = blockIdx.x * BLK + threadIdx.x;
  float s0 = 0.0f, s1 = 0.0f, s2 = 0.0f, s3 = 0.0f;
#pragma unroll 8
  for (int c = 0; c < GSPLIT; c += 4) {
    s0 += partial[(size_t)(c + 0) * P + p];
    s1 += partial[(size_t)(c + 1) * P + p];
    s2 += partial[(size_t)(c + 2) * P + p];
    s3 += partial[(size_t)(c + 3) * P + p];
  }
  out[p] = (s0 + s1) + (s2 + s3);
}

extern "C" void kernel_launch(void* const* d_in, const int* in_sizes, int n_in,
                              void* d_out, int out_size, void* d_ws, size_t ws_size,
                              hipStream_t stream) {
  const float* pos   = (const float*)d_in[0];  // position_rx (P,3)
  const float* mean  = (const float*)d_in[1];  // mean (G,3)
  const float* fdc   = (const float*)d_in[2];  // features_dc (G,1,1)
  const float* frest = (const float*)d_in[3];  // features_rest (G,1,8)
  const float* scal  = (const float*)d_in[4];  // scaling (G,3)
  const float* rot   = (const float*)d_in[5];  // rotation (G,4)
  const float* opac  = (const float*)d_in[6];  // opacity (G,1)
  float* out = (float*)d_out;                  // (P,1) fp32

  float* partial = (float*)d_ws;               // GSPLIT*P*4 = 4 MB

  fused_main<<<dim3(P / PBLK, GSPLIT), BLK, 0, stream>>>(
      pos, mean, fdc, frest, scal, rot, opac, partial);
  reduce_kernel<<<P / BLK, BLK, 0, stream>>>(partial, out);
}

// Round 7
// 38.675 us; speedup vs baseline: 1.5946x; 1.1889x over previous
//
#include <hip/hip_runtime.h>
#include <hip/hip_bf16.h>

// Problem constants (match reference)
constexpr int P = 8192;
constexpr int G = 4096;
constexpr int BLK = 256;
constexpr int GSPLIT = 128;         // G-dimension parallel chunks
constexpr int CHUNK = G / GSPLIT;   // 32 gaussians per chunk
constexpr int PPT = 4;              // points per thread
constexpr int PBLK = BLK * PPT;     // 1024 points per block
constexpr float LOG2E = 1.4426950408889634f;

// ---------------------------------------------------------------------------
// Fused kernel (UNCHANGED from R6): per-block gaussian precompute (first
// CHUNK threads) -> LDS -> VALU-bound pair loop. PPT=4 balances the LDS
// return path (5 x ds_read_b128 ~60 cyc/wave-iter = 12.8 us/CU) against the
// VALU (4 x 32 insts x 2 cyc = 256 cyc/wave-iter = 13.65 us/CU).
// ---------------------------------------------------------------------------
__global__ __launch_bounds__(BLK) void fused_main(
    const float* __restrict__ pos,
    const float* __restrict__ mean, const float* __restrict__ fdc,
    const float* __restrict__ frest, const float* __restrict__ scal,
    const float* __restrict__ rot, const float* __restrict__ opac,
    float* __restrict__ partial) {
  __shared__ float4 sg[CHUNK * 5];

  const int t = threadIdx.x;
  const int c = blockIdx.y;
  const int pbase = blockIdx.x * PBLK + t;

  // Issue the point loads first so their latency overlaps the precompute.
  float px[PPT], py[PPT], pz[PPT], acc[PPT];
#pragma unroll
  for (int k = 0; k < PPT; ++k) {
    const int p = pbase + k * BLK;
    px[k] = pos[p * 3 + 0] * 2.0f - 1.0f;
    py[k] = pos[p * 3 + 1] * 2.0f - 1.0f;
    pz[k] = pos[p * 3 + 2] * 2.0f - 1.0f;
    acc[k] = 0.0f;
  }

  // In-block precompute of this chunk's 32 gaussians.
  if (t < CHUNK) {
    const int g = c * CHUNK + t;

    float qr = rot[g * 4 + 0], qx = rot[g * 4 + 1];
    float qy = rot[g * 4 + 2], qz = rot[g * 4 + 3];
    float qn = 1.0f / sqrtf(qr * qr + qx * qx + qy * qy + qz * qz);
    qr *= qn; qx *= qn; qy *= qn; qz *= qn;

    float R00 = 1.f - 2.f * (qy * qy + qz * qz);
    float R01 = 2.f * (qx * qy - qr * qz);
    float R02 = 2.f * (qx * qz + qr * qy);
    float R10 = 2.f * (qx * qy + qr * qz);
    float R11 = 1.f - 2.f * (qx * qx + qz * qz);
    float R12 = 2.f * (qy * qz - qr * qx);
    float R20 = 2.f * (qx * qz - qr * qy);
    float R21 = 2.f * (qy * qz + qr * qx);
    float R22 = 1.f - 2.f * (qx * qx + qy * qy);

    float sc0 = expf(scal[g * 3 + 0]);
    float sc1 = expf(scal[g * 3 + 1]);
    float sc2 = expf(scal[g * 3 + 2]);
    float iv0 = 1.0f / (sc0 * sc0);
    float iv1 = 1.0f / (sc1 * sc1);
    float iv2 = 1.0f / (sc2 * sc2);

    float s00 = R00 * R00 * iv0 + R01 * R01 * iv1 + R02 * R02 * iv2;
    float s11 = R10 * R10 * iv0 + R11 * R11 * iv1 + R12 * R12 * iv2;
    float s22 = R20 * R20 * iv0 + R21 * R21 * iv1 + R22 * R22 * iv2;
    float s01 = R00 * R10 * iv0 + R01 * R11 * iv1 + R02 * R12 * iv2;
    float s02 = R00 * R20 * iv0 + R01 * R21 * iv1 + R02 * R22 * iv2;
    float s12 = R10 * R20 * iv0 + R11 * R21 * iv1 + R12 * R22 * iv2;

    const float kD = -0.5f * LOG2E;
    const float kO = -LOG2E;

    float alpha = 1.0f / (1.0f + expf(-opac[g]));

    const float C0 = 0.28209479177387814f;
    const float C1 = 0.4886025119029199f;
    float a0 = C0 * fdc[g] * alpha;
    float a1 = -C1 * frest[g * 8 + 0] * alpha;
    float a2 =  C1 * frest[g * 8 + 1] * alpha;
    float a3 = -C1 * frest[g * 8 + 2] * alpha;
    float a4 =  1.0925484305920792f  * frest[g * 8 + 3] * alpha;
    float a5 = -1.0925484305920792f  * frest[g * 8 + 4] * alpha;
    float a6 =  0.31539156525252005f * frest[g * 8 + 5] * alpha;
    float a7 = -1.0925484305920792f  * frest[g * 8 + 6] * alpha;
    float a8 =  0.5462742152960396f  * frest[g * 8 + 7] * alpha;

    float mx = mean[g * 3 + 0], my = mean[g * 3 + 1], mz = mean[g * 3 + 2];

    sg[t * 5 + 0] = make_float4(mx, my, mz, kD * s00);
    sg[t * 5 + 1] = make_float4(kD * s11, kD * s22, kO * s01, kO * s02);
    sg[t * 5 + 2] = make_float4(kO * s12, a0, a1, a2);
    sg[t * 5 + 3] = make_float4(a3, a4, a5, a6);
    sg[t * 5 + 4] = make_float4(a7, a8, 0.f, 0.f);
  }

  __syncthreads();

#pragma unroll 2
  for (int gi = 0; gi < CHUNK; ++gi) {
    const float4 v0 = sg[gi * 5 + 0];
    const float4 v1 = sg[gi * 5 + 1];
    const float4 v2 = sg[gi * 5 + 2];
    const float4 v3 = sg[gi * 5 + 3];
    const float4 v4 = sg[gi * 5 + 4];

#pragma unroll
    for (int k = 0; k < PPT; ++k) {
      const float dx = px[k] - v0.x, dy = py[k] - v0.y, dz = pz[k] - v0.z;
      const float dxx = dx * dx, dyy = dy * dy, dzz = dz * dz;
      const float dxdy = dx * dy, dxdz = dx * dz, dydz = dy * dz;
      const float d2 = dxx + dyy + dzz;

      float m = v0.w * dxx;
      m = fmaf(v1.x, dyy, m);
      m = fmaf(v1.y, dzz, m);
      m = fmaf(v1.z, dxdy, m);
      m = fmaf(v1.w, dxdz, m);
      m = fmaf(v2.x, dydz, m);
      const float gauss = exp2f(m);

      const float inv = __builtin_amdgcn_rsqf(fmaxf(d2, 1e-16f));
      const float inv2 = inv * inv;

      float lin = v3.x * dx;                 // a3*dx
      lin = fmaf(v2.z, dy, lin);             // a1*dy
      lin = fmaf(v2.w, dz, lin);             // a2*dz

      float quad = v3.y * dxdy;              // a4*dxdy
      quad = fmaf(v3.z, dydz, quad);         // a5*dydz
      quad = fmaf(v3.w, fmaf(3.f, dzz, -d2), quad);  // a6*(3dzz-d2)
      quad = fmaf(v4.x, dxdz, quad);         // a7*dxdz
      quad = fmaf(v4.y, dxx - dyy, quad);    // a8*(dxx-dyy)

      float feat = fmaf(inv, lin, v2.y);     // a0 + inv*lin
      feat = fmaf(inv2, quad, feat);

      acc[k] = fmaf(gauss, feat, acc[k]);
    }
  }

#pragma unroll
  for (int k = 0; k < PPT; ++k) {
    partial[(size_t)c * P + pbase + k * BLK] = acc[k];
  }
}

// ---------------------------------------------------------------------------
// Two-level parallel reduction (REWORKED this round). 128 blocks x 256 thr.
// Thread (s = t>>6, lane = t&63) sums the contiguous c-slice [s*32, s*32+32)
// for point p = blk*64 + lane, with 4 independent accumulator chains
// (8 dependent latencies instead of 128). Loads are 256 B coalesced per row.
// LDS tree with fixed combine order -> deterministic.
// ---------------------------------------------------------------------------
__global__ __launch_bounds__(256) void reduce_kernel(
    const float* __restrict__ partial, float* __restrict__ out) {
  __shared__ float red[4][64];
  const int t = threadIdx.x;
  const int lane = t & 63;
  const int s = t >> 6;
  const int p = blockIdx.x * 64 + lane;
  const int cbase = s * 32;

  float a0 = 0.f, a1 = 0.f, a2 = 0.f, a3 = 0.f;
#pragma unroll
  for (int j = 0; j < 32; j += 4) {
    a0 += partial[(size_t)(cbase + j + 0) * P + p];
    a1 += partial[(size_t)(cbase + j + 1) * P + p];
    a2 += partial[(size_t)(cbase + j + 2) * P + p];
    a3 += partial[(size_t)(cbase + j + 3) * P + p];
  }
  red[s][lane] = (a0 + a1) + (a2 + a3);
  __syncthreads();

  if (t < 64) {
    out[p] = (red[0][lane] + red[1][lane]) + (red[2][lane] + red[3][lane]);
  }
}

extern "C" void kernel_launch(void* const* d_in, const int* in_sizes, int n_in,
                              void* d_out, int out_size, void* d_ws, size_t ws_size,
                              hipStream_t stream) {
  const float* pos   = (const float*)d_in[0];  // position_rx (P,3)
  const float* mean  = (const float*)d_in[1];  // mean (G,3)
  const float* fdc   = (const float*)d_in[2];  // features_dc (G,1,1)
  const float* frest = (const float*)d_in[3];  // features_rest (G,1,8)
  const float* scal  = (const float*)d_in[4];  // scaling (G,3)
  const float* rot   = (const float*)d_in[5];  // rotation (G,4)
  const float* opac  = (const float*)d_in[6];  // opacity (G,1)
  float* out = (float*)d_out;                  // (P,1) fp32

  float* partial = (float*)d_ws;               // GSPLIT*P*4 = 4 MB

  fused_main<<<dim3(P / PBLK, GSPLIT), BLK, 0, stream>>>(
      pos, mean, fdc, frest, scal, rot, opac, partial);
  reduce_kernel<<<P / 64, 256, 0, stream>>>(partial, out);
}